// Round 1
// baseline (555.651 us; speedup 1.0000x reference)
//
#include <hip/hip_runtime.h>
#include <cfloat>

// Feature_Correlation_Matching: B=4, N=64*64=4096 points, C=256 dims, fp32.
// out[0:16384)        = prediction (float)
// out[16384:32768)    = NN index written as float (harness reads buffer as float)
#define NB 4
#define NN 4096
#define NC 256
#define TI 64     // rows per block
#define TJ 256    // cols per j-tile
#define KC 16     // K chunk staged in LDS
#define NJT (NN / TJ)   // 16
#define NKC (NC / KC)   // 16

__global__ __launch_bounds__(256) void diag_kernel(const float* __restrict__ x,
                                                   float* __restrict__ diag) {
    const int lane = threadIdx.x & 63;
    const int wave = threadIdx.x >> 6;
    const int row  = (blockIdx.x << 2) + wave;            // 0..16383
    const float4 v = ((const float4*)(x + (size_t)row * NC))[lane];
    float s = v.x * v.x + v.y * v.y + v.z * v.z + v.w * v.w;
    #pragma unroll
    for (int off = 32; off; off >>= 1) s += __shfl_xor(s, off, 64);
    if (lane == 0) diag[row] = s;
}

__global__ __launch_bounds__(256) void fcm_kernel(const float* __restrict__ x,
                                                  const float* __restrict__ diag,
                                                  float* __restrict__ out) {
    __shared__ float As[KC * TI];        // [k][i]   4 KB
    __shared__ float Bs[KC * TJ];        // [k][j]  16 KB
    __shared__ float Ds[TJ];             // diag_j   1 KB
    __shared__ float Scr[TI * 32 * 3];   // merge   24 KB   (total 45 KB)

    const int tid = threadIdx.x;
    const int bx  = blockIdx.x;
    // XCD-locality heuristic: blocks round-robin over 8 XCDs; give XCD pair 2k/2k+1
    // batch k so each XCD's 4 MiB L2 holds exactly one batch's fm (4 MiB).
    const int batch = (bx & 7) >> 1;
    const int tile  = ((bx >> 3) << 1) | (bx & 1);        // 0..63
    const int i0    = tile * TI;

    const float* __restrict__ xb = x + (size_t)batch * NN * NC;
    const float* __restrict__ db = diag + (size_t)batch * NN;

    const int tx = tid & 31;     // owns cols tx*8 .. tx*8+7 of the j-tile
    const int ty = tid >> 5;     // owns rows ty*8 .. ty*8+7 of the i-tile

    // staging assignment (both A and B chunks)
    const int sr  = tid & 63;          // A row
    const int sk0 = (tid >> 6) << 2;   // A k offset within chunk: 0,4,8,12

    // per-thread running top-2 (value) + argmin index, per owned row
    float m1[8], m2[8]; int i1[8];
    #pragma unroll
    for (int r = 0; r < 8; ++r) { m1[r] = FLT_MAX; m2[r] = FLT_MAX; i1[r] = 0; }

    for (int jt = 0; jt < NJT; ++jt) {
        const int j0 = jt * TJ;
        __syncthreads();               // prior insert-phase Ds reads complete
        Ds[tid] = db[j0 + tid];

        float acc[8][8];
        #pragma unroll
        for (int r = 0; r < 8; ++r)
            #pragma unroll
            for (int c = 0; c < 8; ++c) acc[r][c] = 0.0f;

        // register prefetch of chunk 0
        float4 pa  = *(const float4*)(xb + (size_t)(i0 + sr) * NC + sk0);
        const float* bsrc = xb + (size_t)(j0 + tid) * NC;
        float4 pb0 = *(const float4*)(bsrc + 0);
        float4 pb1 = *(const float4*)(bsrc + 4);
        float4 pb2 = *(const float4*)(bsrc + 8);
        float4 pb3 = *(const float4*)(bsrc + 12);

        for (int kc = 0; kc < NKC; ++kc) {
            __syncthreads();           // previous FMA reads of As/Bs done
            // transpose-store into [k][row] layout
            As[(sk0 + 0) * TI + sr] = pa.x;
            As[(sk0 + 1) * TI + sr] = pa.y;
            As[(sk0 + 2) * TI + sr] = pa.z;
            As[(sk0 + 3) * TI + sr] = pa.w;
            Bs[ 0 * TJ + tid] = pb0.x; Bs[ 1 * TJ + tid] = pb0.y;
            Bs[ 2 * TJ + tid] = pb0.z; Bs[ 3 * TJ + tid] = pb0.w;
            Bs[ 4 * TJ + tid] = pb1.x; Bs[ 5 * TJ + tid] = pb1.y;
            Bs[ 6 * TJ + tid] = pb1.z; Bs[ 7 * TJ + tid] = pb1.w;
            Bs[ 8 * TJ + tid] = pb2.x; Bs[ 9 * TJ + tid] = pb2.y;
            Bs[10 * TJ + tid] = pb2.z; Bs[11 * TJ + tid] = pb2.w;
            Bs[12 * TJ + tid] = pb3.x; Bs[13 * TJ + tid] = pb3.y;
            Bs[14 * TJ + tid] = pb3.z; Bs[15 * TJ + tid] = pb3.w;
            if (kc + 1 < NKC) {        // prefetch next chunk; overlaps FMA phase
                const int kb = (kc + 1) * KC;
                pa  = *(const float4*)(xb + (size_t)(i0 + sr) * NC + kb + sk0);
                pb0 = *(const float4*)(bsrc + kb + 0);
                pb1 = *(const float4*)(bsrc + kb + 4);
                pb2 = *(const float4*)(bsrc + kb + 8);
                pb3 = *(const float4*)(bsrc + kb + 12);
            }
            __syncthreads();
            #pragma unroll
            for (int k = 0; k < KC; ++k) {
                float av[8], bv[8];
                *(float4*)&av[0] = *(const float4*)&As[k * TI + ty * 8];
                *(float4*)&av[4] = *(const float4*)&As[k * TI + ty * 8 + 4];
                *(float4*)&bv[0] = *(const float4*)&Bs[k * TJ + tx * 8];
                *(float4*)&bv[4] = *(const float4*)&Bs[k * TJ + tx * 8 + 4];
                #pragma unroll
                for (int r = 0; r < 8; ++r)
                    #pragma unroll
                    for (int c = 0; c < 8; ++c)
                        acc[r][c] = fmaf(av[r], bv[c], acc[r][c]);
            }
        }

        // fold this j-tile into running top-2. Ordering key: diag_j - 2*dot
        // (diag_i is constant per row; relu/sqrt are monotone; self masked).
        #pragma unroll
        for (int c = 0; c < 8; ++c) {
            const int j = j0 + tx * 8 + c;
            const float dj = Ds[tx * 8 + c];
            #pragma unroll
            for (int r = 0; r < 8; ++r) {
                const int ig = i0 + ty * 8 + r;
                float v = fmaf(-2.0f, acc[r][c], dj);
                v = (j == ig) ? FLT_MAX : v;      // exclude self
                const bool lt = v < m1[r];        // strict: ties keep earliest j
                m2[r] = fminf(m2[r], fmaxf(m1[r], v));
                m1[r] = fminf(m1[r], v);
                i1[r] = lt ? j : i1[r];
            }
        }
    }

    // cross-thread merge over the 32 column-slices
    __syncthreads();
    #pragma unroll
    for (int r = 0; r < 8; ++r) {
        float* s = &Scr[((ty * 8 + r) * 32 + tx) * 3];
        s[0] = m1[r]; s[1] = __int_as_float(i1[r]); s[2] = m2[r];
    }
    __syncthreads();
    if (tid < TI) {
        float M1 = FLT_MAX, M2 = FLT_MAX; int I1 = 0;
        for (int t = 0; t < 32; ++t) {
            const float* s = &Scr[(tid * 32 + t) * 3];
            const float v1 = s[0]; const int ii = __float_as_int(s[1]);
            const float v2 = s[2];
            if (v1 < M1 || (v1 == M1 && ii < I1)) {   // stable top_k tie-break
                M2 = fminf(M2, M1); M1 = v1; I1 = ii;
            } else {
                M2 = fminf(M2, v1);
            }
            M2 = fminf(M2, v2);
        }
        const int   gi = i0 + tid;
        const float di = db[gi];
        const float d1 = sqrtf(fmaxf(di + M1, 0.0f) + 1e-9f);   // NN distance
        const float d2 = sqrtf(fmaxf(di + M2, 0.0f) + 1e-9f);   // 2nd-NN distance
        const float e  = expf(d1);
        const float pred = (d1 / d2 < 0.6f) ? 2.0f / (1.0f + e)
                                            : 2.0f / (1.0f + 2.0f * e);
        out[(size_t)batch * NN + gi] = pred;
        out[(size_t)NB * NN + (size_t)batch * NN + gi] = (float)I1;
    }
}

extern "C" void kernel_launch(void* const* d_in, const int* in_sizes, int n_in,
                              void* d_out, int out_size, void* d_ws, size_t ws_size,
                              hipStream_t stream) {
    const float* x   = (const float*)d_in[0];
    float* diag      = (float*)d_ws;          // 16384 floats = 64 KB scratch
    float* out       = (float*)d_out;         // 32768 floats
    diag_kernel<<<dim3(NB * NN / 4), dim3(256), 0, stream>>>(x, diag);
    fcm_kernel<<<dim3(256), dim3(256), 0, stream>>>(x, diag, out);
}

// Round 2
// 180.488 us; speedup vs baseline: 3.0786x; 3.0786x over previous
//
#include <hip/hip_runtime.h>
#include <cfloat>

#define NB 4
#define NN 4096
#define NC 256

typedef _Float16 f16;
typedef _Float16 f16x8 __attribute__((ext_vector_type(8)));
typedef float f32x4 __attribute__((ext_vector_type(4)));

__device__ __forceinline__ void gl_lds16(const void* g, void* l) {
    __builtin_amdgcn_global_load_lds(
        (const __attribute__((address_space(1))) unsigned int*)g,
        (__attribute__((address_space(3))) unsigned int*)l, 16, 0, 0);
}

// ---------------- prep: fp32 -> f16 hi/lo split + diag ----------------
__global__ __launch_bounds__(256) void prep_kernel(const float* __restrict__ x,
                                                   f16* __restrict__ xh,
                                                   f16* __restrict__ xl,
                                                   float* __restrict__ diag) {
    const int lane = threadIdx.x & 63;
    const int wave = threadIdx.x >> 6;
    const int row  = (blockIdx.x << 2) + wave;            // 0..16383
    const float4 v = ((const float4*)(x + (size_t)row * NC))[lane];
    union { f16 h[4]; uint2 u; } H, L;
    float vv[4] = {v.x, v.y, v.z, v.w};
    float s = 0.f;
    #pragma unroll
    for (int k = 0; k < 4; ++k) {
        H.h[k] = (f16)vv[k];
        L.h[k] = (f16)(vv[k] - (float)H.h[k]);
        s = fmaf(vv[k], vv[k], s);
    }
    *(uint2*)(xh + (size_t)row * NC + lane * 4) = H.u;
    *(uint2*)(xl + (size_t)row * NC + lane * 4) = L.u;
    #pragma unroll
    for (int off = 32; off; off >>= 1) s += __shfl_xor(s, off, 64);
    if (lane == 0) diag[row] = s;
}

// ---------------- main MFMA kernel ----------------
#define TI 64
#define TJ 256
#define KCB 64

__global__ __launch_bounds__(512, 2) void fcm_mfma(const f16* __restrict__ xh,
                                                   const f16* __restrict__ xl,
                                                   const float* __restrict__ diag,
                                                   float* __restrict__ out) {
    __shared__ f16 Ah[TI * NC];          // 32 KB  persistent A hi (swizzled)
    __shared__ f16 Al[TI * NC];          // 32 KB  persistent A lo
    __shared__ f16 Bh[TJ * KCB];         // 32 KB  B hi chunk
    __shared__ f16 Bl[TJ * KCB];         // 32 KB  B lo chunk
    __shared__ float Ds[TJ];             // 1 KB   diag_j
    __shared__ float Scr[TI * 4 * 3];    // 3 KB   cross-wave merge

    const int tid   = threadIdx.x;
    const int bx    = blockIdx.x;
    const int batch = (bx & 7) >> 1;                  // batch -> XCD pair
    const int band  = ((bx >> 3) << 1) | (bx & 1);    // 0..63
    const int i0    = band * TI;

    const f16* __restrict__ xhb = xh + (size_t)batch * NN * NC;
    const f16* __restrict__ xlb = xl + (size_t)batch * NN * NC;
    const float* __restrict__ db = diag + (size_t)batch * NN;

    const int w    = tid >> 6;
    const int lane = tid & 63;
    const int quad = lane >> 4;
    const int l15  = lane & 15;
    const int wy   = w >> 2;      // row half (0..1)
    const int wx   = w & 3;       // col quarter (0..3)
    const int sw   = l15 & 7;     // fragment swizzle key

    // ---- A stage (once): LDS[row][granule ^ (row&7)] = x[i0+row][granule] ----
    {
        const int rsub = lane >> 5;        // 0/1
        const int s    = lane & 31;
        #pragma unroll
        for (int it = 0; it < 4; ++it) {
            const int t  = w * 4 + it;     // 0..31, 2 rows each
            const int rg = t * 2 + rsub;
            const int g  = s ^ (rg & 7);
            const size_t goff = (size_t)(i0 + rg) * NC + g * 8;
            gl_lds16(xhb + goff, Ah + t * 512);
            gl_lds16(xlb + goff, Al + t * 512);
        }
    }

    // B staging lane constants: 8 cols / wave-instr, 128 B k-window each
    const int bjc = lane >> 3;             // col within group
    const int bgg = (lane & 7) ^ bjc;      // swizzled source granule

    // running top-2 (+argmin) for the lane's 8 row-slots
    float m1[8], m2[8]; int i1[8];
    #pragma unroll
    for (int r = 0; r < 8; ++r) { m1[r] = FLT_MAX; m2[r] = FLT_MAX; i1[r] = 0x7fffffff; }

    for (int jt = 0; jt < NN / TJ; ++jt) {
        const int j0 = jt * TJ;
        f32x4 acc[2][4];
        #pragma unroll
        for (int rt = 0; rt < 2; ++rt)
            #pragma unroll
            for (int ct = 0; ct < 4; ++ct)
                acc[rt][ct] = (f32x4){0.f, 0.f, 0.f, 0.f};

        for (int kc = 0; kc < NC / KCB; ++kc) {
            __syncthreads();               // prior chunk's frag reads done
            #pragma unroll
            for (int it = 0; it < 4; ++it) {
                const int t  = w * 4 + it;                  // 0..31, 8 cols each
                const int jc = t * 8 + bjc;
                const size_t goff = (size_t)(j0 + jc) * NC + kc * KCB + bgg * 8;
                gl_lds16(xhb + goff, Bh + t * 512);
                gl_lds16(xlb + goff, Bl + t * 512);
            }
            if (kc == 0 && tid < TJ) Ds[tid] = db[j0 + tid];
            __syncthreads();               // drains vmcnt -> B (and A) ready
            #pragma unroll
            for (int ks = 0; ks < 2; ++ks) {
                f16x8 afh[2], afl[2], bfh[4], bfl[4];
                #pragma unroll
                for (int rt = 0; rt < 2; ++rt) {
                    const int r  = wy * 32 + rt * 16 + l15;
                    const int gA = (kc * 8 + ks * 4 + quad) ^ sw;
                    afh[rt] = *(const f16x8*)&Ah[r * NC + gA * 8];
                    afl[rt] = *(const f16x8*)&Al[r * NC + gA * 8];
                }
                #pragma unroll
                for (int ct = 0; ct < 4; ++ct) {
                    const int c  = wx * 64 + ct * 16 + l15;
                    const int gB = (ks * 4 + quad) ^ sw;
                    bfh[ct] = *(const f16x8*)&Bh[c * KCB + gB * 8];
                    bfl[ct] = *(const f16x8*)&Bl[c * KCB + gB * 8];
                }
                #pragma unroll
                for (int rt = 0; rt < 2; ++rt)
                    #pragma unroll
                    for (int ct = 0; ct < 4; ++ct) {
                        acc[rt][ct] = __builtin_amdgcn_mfma_f32_16x16x32_f16(afh[rt], bfh[ct], acc[rt][ct], 0, 0, 0);
                        acc[rt][ct] = __builtin_amdgcn_mfma_f32_16x16x32_f16(afh[rt], bfl[ct], acc[rt][ct], 0, 0, 0);
                        acc[rt][ct] = __builtin_amdgcn_mfma_f32_16x16x32_f16(afl[rt], bfh[ct], acc[rt][ct], 0, 0, 0);
                    }
            }
        }

        // fold j-tile into running top-2; key = diag_j - 2*dot (monotone in dist)
        #pragma unroll
        for (int ct = 0; ct < 4; ++ct) {
            const int colb = wx * 64 + ct * 16 + l15;
            const float dj = Ds[colb];
            const int col  = j0 + colb;
            #pragma unroll
            for (int rt = 0; rt < 2; ++rt) {
                #pragma unroll
                for (int p = 0; p < 4; ++p) {
                    const int rglob = i0 + wy * 32 + rt * 16 + quad * 4 + p;
                    float v = fmaf(-2.0f, acc[rt][ct][p], dj);
                    v = (col == rglob) ? FLT_MAX : v;       // mask self
                    const int slot = rt * 4 + p;
                    const bool lt = v < m1[slot];           // strict: keep earliest j
                    m2[slot] = fminf(m2[slot], fmaxf(m1[slot], v));
                    m1[slot] = fminf(m1[slot], v);
                    i1[slot] = lt ? col : i1[slot];
                }
            }
        }
    }

    // butterfly merge across the 16 col-lanes holding the same rows
    #pragma unroll
    for (int s = 0; s < 8; ++s) {
        float a1 = m1[s], a2 = m2[s]; int ai = i1[s];
        #pragma unroll
        for (int msk = 1; msk < 16; msk <<= 1) {
            const float o1 = __shfl_xor(a1, msk, 64);
            const float o2 = __shfl_xor(a2, msk, 64);
            const int   oi = __shfl_xor(ai, msk, 64);
            const bool take = (o1 < a1) || (o1 == a1 && oi < ai);
            const float keep = take ? a1 : o1;
            a2 = fminf(fminf(a2, o2), keep);
            a1 = take ? o1 : a1;
            ai = take ? oi : ai;
        }
        m1[s] = a1; m2[s] = a2; i1[s] = ai;
    }
    if (l15 == 0) {
        #pragma unroll
        for (int s = 0; s < 8; ++s) {
            const int rloc = wy * 32 + (s >> 2) * 16 + quad * 4 + (s & 3);
            float* p = &Scr[(rloc * 4 + wx) * 3];
            p[0] = m1[s]; p[1] = __int_as_float(i1[s]); p[2] = m2[s];
        }
    }
    __syncthreads();
    if (tid < TI) {
        float M1 = FLT_MAX, M2 = FLT_MAX; int I1 = 0x7fffffff;
        #pragma unroll
        for (int t = 0; t < 4; ++t) {
            const float* p = &Scr[(tid * 4 + t) * 3];
            const float o1 = p[0]; const int oi = __float_as_int(p[1]); const float o2 = p[2];
            const bool take = (o1 < M1) || (o1 == M1 && oi < I1);
            const float keep = take ? M1 : o1;
            M2 = fminf(fminf(M2, o2), keep);
            M1 = take ? o1 : M1;
            I1 = take ? oi : I1;
        }
        const int   gi = i0 + tid;
        const float di = db[gi];
        const float d1 = sqrtf(fmaxf(di + M1, 0.0f) + 1e-9f);
        const float d2 = sqrtf(fmaxf(di + M2, 0.0f) + 1e-9f);
        const float e  = expf(d1);
        const float pred = (d1 / d2 < 0.6f) ? 2.0f / (1.0f + e)
                                            : 2.0f / (1.0f + 2.0f * e);
        out[(size_t)batch * NN + gi] = pred;
        out[(size_t)NB * NN + (size_t)batch * NN + gi] = (float)I1;
    }
}

// ---------------- fp32 fallback (round-1, passed) if ws too small ----------------
__global__ __launch_bounds__(256) void diag_kernel(const float* __restrict__ x,
                                                   float* __restrict__ diag) {
    const int lane = threadIdx.x & 63;
    const int wave = threadIdx.x >> 6;
    const int row  = (blockIdx.x << 2) + wave;
    const float4 v = ((const float4*)(x + (size_t)row * NC))[lane];
    float s = v.x * v.x + v.y * v.y + v.z * v.z + v.w * v.w;
    #pragma unroll
    for (int off = 32; off; off >>= 1) s += __shfl_xor(s, off, 64);
    if (lane == 0) diag[row] = s;
}

#define FTI 64
#define FTJ 256
#define FKC 16

__global__ __launch_bounds__(256) void fcm_fallback(const float* __restrict__ x,
                                                    const float* __restrict__ diag,
                                                    float* __restrict__ out) {
    __shared__ float As[FKC * FTI];
    __shared__ float Bs[FKC * FTJ];
    __shared__ float Dsf[FTJ];
    __shared__ float Scrf[FTI * 32 * 3];

    const int tid = threadIdx.x;
    const int bx  = blockIdx.x;
    const int batch = (bx & 7) >> 1;
    const int tile  = ((bx >> 3) << 1) | (bx & 1);
    const int i0    = tile * FTI;
    const float* __restrict__ xb = x + (size_t)batch * NN * NC;
    const float* __restrict__ db = diag + (size_t)batch * NN;
    const int tx = tid & 31;
    const int ty = tid >> 5;
    const int sr  = tid & 63;
    const int sk0 = (tid >> 6) << 2;

    float m1[8], m2[8]; int i1[8];
    #pragma unroll
    for (int r = 0; r < 8; ++r) { m1[r] = FLT_MAX; m2[r] = FLT_MAX; i1[r] = 0; }

    for (int jt = 0; jt < NN / FTJ; ++jt) {
        const int j0 = jt * FTJ;
        __syncthreads();
        Dsf[tid] = db[j0 + tid];
        float acc[8][8];
        #pragma unroll
        for (int r = 0; r < 8; ++r)
            #pragma unroll
            for (int c = 0; c < 8; ++c) acc[r][c] = 0.0f;
        float4 pa  = *(const float4*)(xb + (size_t)(i0 + sr) * NC + sk0);
        const float* bsrc = xb + (size_t)(j0 + tid) * NC;
        float4 pb0 = *(const float4*)(bsrc + 0);
        float4 pb1 = *(const float4*)(bsrc + 4);
        float4 pb2 = *(const float4*)(bsrc + 8);
        float4 pb3 = *(const float4*)(bsrc + 12);
        for (int kc = 0; kc < NC / FKC; ++kc) {
            __syncthreads();
            As[(sk0 + 0) * FTI + sr] = pa.x;
            As[(sk0 + 1) * FTI + sr] = pa.y;
            As[(sk0 + 2) * FTI + sr] = pa.z;
            As[(sk0 + 3) * FTI + sr] = pa.w;
            Bs[ 0 * FTJ + tid] = pb0.x; Bs[ 1 * FTJ + tid] = pb0.y;
            Bs[ 2 * FTJ + tid] = pb0.z; Bs[ 3 * FTJ + tid] = pb0.w;
            Bs[ 4 * FTJ + tid] = pb1.x; Bs[ 5 * FTJ + tid] = pb1.y;
            Bs[ 6 * FTJ + tid] = pb1.z; Bs[ 7 * FTJ + tid] = pb1.w;
            Bs[ 8 * FTJ + tid] = pb2.x; Bs[ 9 * FTJ + tid] = pb2.y;
            Bs[10 * FTJ + tid] = pb2.z; Bs[11 * FTJ + tid] = pb2.w;
            Bs[12 * FTJ + tid] = pb3.x; Bs[13 * FTJ + tid] = pb3.y;
            Bs[14 * FTJ + tid] = pb3.z; Bs[15 * FTJ + tid] = pb3.w;
            if (kc + 1 < NC / FKC) {
                const int kb = (kc + 1) * FKC;
                pa  = *(const float4*)(xb + (size_t)(i0 + sr) * NC + kb + sk0);
                pb0 = *(const float4*)(bsrc + kb + 0);
                pb1 = *(const float4*)(bsrc + kb + 4);
                pb2 = *(const float4*)(bsrc + kb + 8);
                pb3 = *(const float4*)(bsrc + kb + 12);
            }
            __syncthreads();
            #pragma unroll
            for (int k = 0; k < FKC; ++k) {
                float av[8], bv[8];
                *(float4*)&av[0] = *(const float4*)&As[k * FTI + ty * 8];
                *(float4*)&av[4] = *(const float4*)&As[k * FTI + ty * 8 + 4];
                *(float4*)&bv[0] = *(const float4*)&Bs[k * FTJ + tx * 8];
                *(float4*)&bv[4] = *(const float4*)&Bs[k * FTJ + tx * 8 + 4];
                #pragma unroll
                for (int r = 0; r < 8; ++r)
                    #pragma unroll
                    for (int c = 0; c < 8; ++c)
                        acc[r][c] = fmaf(av[r], bv[c], acc[r][c]);
            }
        }
        #pragma unroll
        for (int c = 0; c < 8; ++c) {
            const int j = j0 + tx * 8 + c;
            const float dj = Dsf[tx * 8 + c];
            #pragma unroll
            for (int r = 0; r < 8; ++r) {
                const int ig = i0 + ty * 8 + r;
                float v = fmaf(-2.0f, acc[r][c], dj);
                v = (j == ig) ? FLT_MAX : v;
                const bool lt = v < m1[r];
                m2[r] = fminf(m2[r], fmaxf(m1[r], v));
                m1[r] = fminf(m1[r], v);
                i1[r] = lt ? j : i1[r];
            }
        }
    }
    __syncthreads();
    #pragma unroll
    for (int r = 0; r < 8; ++r) {
        float* s = &Scrf[((ty * 8 + r) * 32 + tx) * 3];
        s[0] = m1[r]; s[1] = __int_as_float(i1[r]); s[2] = m2[r];
    }
    __syncthreads();
    if (tid < FTI) {
        float M1 = FLT_MAX, M2 = FLT_MAX; int I1 = 0;
        for (int t = 0; t < 32; ++t) {
            const float* s = &Scrf[(tid * 32 + t) * 3];
            const float v1 = s[0]; const int ii = __float_as_int(s[1]);
            const float v2 = s[2];
            if (v1 < M1 || (v1 == M1 && ii < I1)) {
                M2 = fminf(M2, M1); M1 = v1; I1 = ii;
            } else {
                M2 = fminf(M2, v1);
            }
            M2 = fminf(M2, v2);
        }
        const int   gi = i0 + tid;
        const float di = db[gi];
        const float d1 = sqrtf(fmaxf(di + M1, 0.0f) + 1e-9f);
        const float d2 = sqrtf(fmaxf(di + M2, 0.0f) + 1e-9f);
        const float e  = expf(d1);
        const float pred = (d1 / d2 < 0.6f) ? 2.0f / (1.0f + e)
                                            : 2.0f / (1.0f + 2.0f * e);
        out[(size_t)batch * NN + gi] = pred;
        out[(size_t)NB * NN + (size_t)batch * NN + gi] = (float)I1;
    }
}

extern "C" void kernel_launch(void* const* d_in, const int* in_sizes, int n_in,
                              void* d_out, int out_size, void* d_ws, size_t ws_size,
                              hipStream_t stream) {
    const float* x = (const float*)d_in[0];
    float* out     = (float*)d_out;
    const size_t n_elem = (size_t)NB * NN * NC;
    const size_t need   = n_elem * 2 * 2 + (size_t)NB * NN * 4;   // hi+lo f16 + diag
    if (ws_size >= need) {
        f16*   xh   = (f16*)d_ws;
        f16*   xl   = xh + n_elem;
        float* diag = (float*)(xl + n_elem);
        prep_kernel<<<dim3(NB * NN / 4), dim3(256), 0, stream>>>(x, xh, xl, diag);
        fcm_mfma<<<dim3(256), dim3(512), 0, stream>>>(xh, xl, diag, out);
    } else {
        float* diag = (float*)d_ws;
        diag_kernel<<<dim3(NB * NN / 4), dim3(256), 0, stream>>>(x, diag);
        fcm_fallback<<<dim3(256), dim3(256), 0, stream>>>(x, diag, out);
    }
}